// Round 6
// baseline (57.908 us; speedup 1.0000x reference)
//
#include <hip/hip_runtime.h>

#define H_STEPS 200
#define DT 0.01f
#define K_SPRING 100.0f
#define NCH 6   // six 32-step chunks; last 8 steps via direct per-lane loads

__device__ __forceinline__ void step(float u, float& x1, float& v1,
                                     float& x2, float& v2) {
    float pen     = x1 + 1.0f - x2;
    float contact = fmaxf(pen, 0.0f);
    float Fc      = -K_SPRING * contact;
    float F1      = u + Fc - v1;      // C = 1
    float F2      = -Fc - v2;
    v1 += F1 * DT;
    v2 += F2 * DT;
    x1 += v1 * DT;
    x2 += v2 * DT;
}

// {coalesced, deep}: 48 coalesced loads (8 rows x 128B per instr) reg-staged
// up front; sched_barrier(0) pins them there (R4 failure: MachineScheduler
// sank them, VGPR=52). Per-chunk wave-local LDS transpose, XOR-swizzled.
// No __syncthreads anywhere (would drain vmcnt(0) and kill the pipeline).
__global__ __launch_bounds__(256, 2)   // 2 waves/EU -> 256-VGPR budget
void pushing_env_kernel(const float* __restrict__ u_seq,
                        const float* __restrict__ x1_0,
                        const float* __restrict__ v1_0,
                        const float* __restrict__ x2_0,
                        const float* __restrict__ v2_0,
                        const float* __restrict__ goal,
                        float* __restrict__ out, int B) {
    __shared__ float4 lds[4][64 * 8];   // 8KB per wave, 32KB per block
    const int tid  = threadIdx.x;
    const int wave = tid >> 6;
    const int lane = tid & 63;
    const int b0w  = blockIdx.x * 256 + wave * 64;  // wave's first batch row
    const int b    = b0w + lane;

    // States first: in-order completion precedes staged loads, so their use
    // needs only a counted vmcnt, not a drain.
    float x1 = x1_0[b];
    float v1 = v1_0[b];
    float x2 = x2_0[b];
    float v2 = v2_0[b];
    const float g = goal[0];   // uniform -> s_load

    const int lrow = lane >> 3;   // row-in-group selector (0..7)
    const int lq   = lane & 7;    // qword slot within chunk (0..7)
    const float* ubase = u_seq + (size_t)b0w * H_STEPS;

    // Staged coalesced loads: instr (c,k) covers rows k*8..k*8+7, qwords
    // 8c..8c+7 (8 x 128B contiguous segments per wave instr).
    float4 r[NCH][8];
    #pragma unroll
    for (int c = 0; c < NCH; ++c) {
        #pragma unroll
        for (int k = 0; k < 8; ++k) {
            const int row = k * 8 + lrow;
            r[c][k] = *reinterpret_cast<const float4*>(
                ubase + (size_t)row * H_STEPS + (8 * c + lq) * 4);
        }
    }
    // Tail (steps 192..199): own row, 2 divergent loads - issued last.
    const float4* urow = reinterpret_cast<const float4*>(
        u_seq + (size_t)b * H_STEPS);
    float4 t0 = urow[48];
    float4 t1 = urow[49];

    // THE PIN: nothing may be scheduled across this point. All 50 loads above
    // stay issued here; uses below get counted vmcnt waits per chunk.
    __builtin_amdgcn_sched_barrier(0);

    float4* lw = lds[wave];   // wave-private region: no cross-wave sharing

    #pragma unroll
    for (int c = 0; c < NCH; ++c) {
        // Write phase: reg k holds row R=k*8+lrow, slot lq -> swizzled qword.
        #pragma unroll
        for (int k = 0; k < 8; ++k) {
            const int R = k * 8 + lrow;
            lw[R * 8 + (lq ^ lrow)] = r[c][k];   // R&7 == lrow
        }
        __builtin_amdgcn_sched_barrier(0);  // writes before reads (cross-lane)
        // Read + compute: lane l owns row l; q-th read = qwords 8c+q.
        #pragma unroll
        for (int q = 0; q < 8; ++q) {
            float4 u4 = lw[lane * 8 + (q ^ (lane & 7))];
            step(u4.x, x1, v1, x2, v2);
            step(u4.y, x1, v1, x2, v2);
            step(u4.z, x1, v1, x2, v2);
            step(u4.w, x1, v1, x2, v2);
        }
        __builtin_amdgcn_sched_barrier(0);  // reads retire before next writes
    }

    // Tail 8 steps from direct registers.
    step(t0.x, x1, v1, x2, v2);
    step(t0.y, x1, v1, x2, v2);
    step(t0.z, x1, v1, x2, v2);
    step(t0.w, x1, v1, x2, v2);
    step(t1.x, x1, v1, x2, v2);
    step(t1.y, x1, v1, x2, v2);
    step(t1.z, x1, v1, x2, v2);
    step(t1.w, x1, v1, x2, v2);

    float d = x2 - g;
    out[b]         = d * d;   // loss
    out[B + b]     = x1;
    out[2 * B + b] = x2;
}

extern "C" void kernel_launch(void* const* d_in, const int* in_sizes, int n_in,
                              void* d_out, int out_size, void* d_ws, size_t ws_size,
                              hipStream_t stream) {
    const float* u_seq = (const float*)d_in[0];
    const float* x1_0  = (const float*)d_in[1];
    const float* v1_0  = (const float*)d_in[2];
    const float* x2_0  = (const float*)d_in[3];
    const float* v2_0  = (const float*)d_in[4];
    const float* goal  = (const float*)d_in[5];
    float* out = (float*)d_out;

    const int B = in_sizes[1];  // 131072
    const int grid = B / 256;   // 512 blocks x 256 threads
    pushing_env_kernel<<<grid, 256, 0, stream>>>(u_seq, x1_0, v1_0, x2_0,
                                                 v2_0, goal, out, B);
}

// Round 7
// 26.707 us; speedup vs baseline: 2.1682x; 2.1682x over previous
//
#include <hip/hip_runtime.h>

#define H_STEPS 200
#define DT 0.01f
#define K_SPRING 100.0f

__device__ __forceinline__ void step(float u, float& x1, float& v1,
                                     float& x2, float& v2) {
    float pen     = x1 + 1.0f - x2;
    float contact = fmaxf(pen, 0.0f);
    float Fc      = -K_SPRING * contact;
    float F1      = u + Fc - v1;      // C = 1
    float F2      = -Fc - v2;
    v1 += F1 * DT;
    v2 += F2 * DT;
    x1 += v1 * DT;
    x2 += v2 * DT;
}

// {coalesced, deep} without an array: 48 NAMED float4 registers (no alloca ->
// no scratch demotion, which killed R4/R5: VGPR=52 + 100MB scratch WRITE).
// Each load instr covers 8 rows x 128B contiguous. All 50 issue before the
// sched_barrier(0) pin; per-chunk wave-local XOR-swizzled LDS transpose.
// No __syncthreads anywhere (would drain vmcnt and kill the pipeline).
__global__ __launch_bounds__(256, 2)   // 2 waves/EU -> 256-VGPR budget
void pushing_env_kernel(const float* __restrict__ u_seq,
                        const float* __restrict__ x1_0,
                        const float* __restrict__ v1_0,
                        const float* __restrict__ x2_0,
                        const float* __restrict__ v2_0,
                        const float* __restrict__ goal,
                        float* __restrict__ out, int B) {
    __shared__ float4 lds[4][64 * 8];   // 8KB per wave, 32KB per block
    const int tid  = threadIdx.x;
    const int wave = tid >> 6;
    const int lane = tid & 63;
    const int b0w  = blockIdx.x * 256 + wave * 64;  // wave's first batch row
    const int b    = b0w + lane;

    // States first: oldest in vmcnt order, covered by any later counted wait.
    float x1 = x1_0[b];
    float v1 = v1_0[b];
    float x2 = x2_0[b];
    float v2 = v2_0[b];
    const float g = goal[0];

    const int lrow = lane >> 3;   // row-in-group selector (0..7)
    const int lq   = lane & 7;    // qword slot within chunk (0..7)
    const float* ubase = u_seq + (size_t)b0w * H_STEPS;

    // Load (c,k): rows k*8..k*8+7, qwords 8c..8c+7 -> 8 x 128B segments/instr.
#define LDQ(c, k) (*reinterpret_cast<const float4*>( \
        ubase + (size_t)((k) * 8 + lrow) * H_STEPS + (8 * (c) + lq) * 4))
#define ST(c) \
    float4 r##c##0 = LDQ(c,0), r##c##1 = LDQ(c,1), r##c##2 = LDQ(c,2), \
           r##c##3 = LDQ(c,3), r##c##4 = LDQ(c,4), r##c##5 = LDQ(c,5), \
           r##c##6 = LDQ(c,6), r##c##7 = LDQ(c,7);

    ST(0) ST(1) ST(2) ST(3) ST(4) ST(5)            // 48 loads, all in flight

    // Tail (steps 192..199): own row, 2 divergent loads, issued last.
    const float4* urow = reinterpret_cast<const float4*>(
        u_seq + (size_t)b * H_STEPS);
    float4 t0 = urow[48];
    float4 t1 = urow[49];

    // THE PIN: nothing may cross; loads stay issued here, uses below get
    // counted vmcnt waits per chunk.
    __builtin_amdgcn_sched_barrier(0);

    float4* lw = lds[wave];                 // wave-private: no cross-wave race
    const int waddr = lrow * 8 + (lq ^ lrow);  // + k*64 per write
    const int raddr = lane * 8;                // + (q^lq) per read

#define WRITE8(c) \
    lw[0*64 + waddr] = r##c##0; lw[1*64 + waddr] = r##c##1; \
    lw[2*64 + waddr] = r##c##2; lw[3*64 + waddr] = r##c##3; \
    lw[4*64 + waddr] = r##c##4; lw[5*64 + waddr] = r##c##5; \
    lw[6*64 + waddr] = r##c##6; lw[7*64 + waddr] = r##c##7;

#define CHUNK(c) \
    WRITE8(c) \
    __builtin_amdgcn_sched_barrier(0); /* writes precede cross-lane reads */ \
    _Pragma("unroll") \
    for (int q = 0; q < 8; ++q) { \
        float4 u4 = lw[raddr + (q ^ lq)]; \
        step(u4.x, x1, v1, x2, v2); \
        step(u4.y, x1, v1, x2, v2); \
        step(u4.z, x1, v1, x2, v2); \
        step(u4.w, x1, v1, x2, v2); \
    } \
    __builtin_amdgcn_sched_barrier(0); /* reads retire before next writes */

    CHUNK(0) CHUNK(1) CHUNK(2) CHUNK(3) CHUNK(4) CHUNK(5)

    // Tail 8 steps from direct registers.
    step(t0.x, x1, v1, x2, v2);
    step(t0.y, x1, v1, x2, v2);
    step(t0.z, x1, v1, x2, v2);
    step(t0.w, x1, v1, x2, v2);
    step(t1.x, x1, v1, x2, v2);
    step(t1.y, x1, v1, x2, v2);
    step(t1.z, x1, v1, x2, v2);
    step(t1.w, x1, v1, x2, v2);

    float d = x2 - g;
    out[b]         = d * d;   // loss
    out[B + b]     = x1;
    out[2 * B + b] = x2;
}

extern "C" void kernel_launch(void* const* d_in, const int* in_sizes, int n_in,
                              void* d_out, int out_size, void* d_ws, size_t ws_size,
                              hipStream_t stream) {
    const float* u_seq = (const float*)d_in[0];
    const float* x1_0  = (const float*)d_in[1];
    const float* v1_0  = (const float*)d_in[2];
    const float* x2_0  = (const float*)d_in[3];
    const float* v2_0  = (const float*)d_in[4];
    const float* goal  = (const float*)d_in[5];
    float* out = (float*)d_out;

    const int B = in_sizes[1];  // 131072
    const int grid = B / 256;   // 512 blocks x 256 threads
    pushing_env_kernel<<<grid, 256, 0, stream>>>(u_seq, x1_0, v1_0, x2_0,
                                                 v2_0, goal, out, B);
}

// Round 8
// 24.650 us; speedup vs baseline: 2.3492x; 1.0835x over previous
//
#include <hip/hip_runtime.h>

#define H_STEPS 200
#define DT 0.01f
#define K_SPRING 100.0f

__device__ __forceinline__ void step(float u, float& x1, float& v1,
                                     float& x2, float& v2) {
    float pen     = x1 + 1.0f - x2;
    float contact = fmaxf(pen, 0.0f);
    float Fc      = -K_SPRING * contact;
    float F1      = u + Fc - v1;      // C = 1
    float F2      = -Fc - v2;
    v1 += F1 * DT;
    v2 += F2 * DT;
    x1 += v1 * DT;
    x2 += v2 * DT;
}

// {divergent, deep-50, no LDS}: one thread per row; the whole 800B row in 50
// NAMED float4 registers (named scalars bypass PromoteAlloca — the R4/R5
// scratch-demotion trap), pinned by sched_barrier(0) so the full 50-deep
// pipeline really exists (R3's array version left depth to compiler whim).
// Consumption in issue order -> progressive counted vmcnt, never a drain.
__global__ __launch_bounds__(256, 2)   // 2 waves/EU -> 256-VGPR budget
void pushing_env_kernel(const float* __restrict__ u_seq,
                        const float* __restrict__ x1_0,
                        const float* __restrict__ v1_0,
                        const float* __restrict__ x2_0,
                        const float* __restrict__ v2_0,
                        const float* __restrict__ goal,
                        float* __restrict__ out, int B) {
    int b = blockIdx.x * blockDim.x + threadIdx.x;

    // States issue first: oldest in vmcnt order, covered by later counted waits.
    float x1 = x1_0[b];
    float v1 = v1_0[b];
    float x2 = x2_0[b];
    float v2 = v2_0[b];
    const float g = goal[0];

    const float4* u = reinterpret_cast<const float4*>(u_seq + (size_t)b * H_STEPS);

#define LD(q) float4 u##q = u[q];
    LD(0)  LD(1)  LD(2)  LD(3)  LD(4)  LD(5)  LD(6)  LD(7)  LD(8)  LD(9)
    LD(10) LD(11) LD(12) LD(13) LD(14) LD(15) LD(16) LD(17) LD(18) LD(19)
    LD(20) LD(21) LD(22) LD(23) LD(24) LD(25) LD(26) LD(27) LD(28) LD(29)
    LD(30) LD(31) LD(32) LD(33) LD(34) LD(35) LD(36) LD(37) LD(38) LD(39)
    LD(40) LD(41) LD(42) LD(43) LD(44) LD(45) LD(46) LD(47) LD(48) LD(49)

    // THE PIN: all 50 loads stay issued here; uses below wait via counted vmcnt.
    __builtin_amdgcn_sched_barrier(0);

#define S(q) \
    step(u##q.x, x1, v1, x2, v2); \
    step(u##q.y, x1, v1, x2, v2); \
    step(u##q.z, x1, v1, x2, v2); \
    step(u##q.w, x1, v1, x2, v2);

    S(0)  S(1)  S(2)  S(3)  S(4)  S(5)  S(6)  S(7)  S(8)  S(9)
    S(10) S(11) S(12) S(13) S(14) S(15) S(16) S(17) S(18) S(19)
    S(20) S(21) S(22) S(23) S(24) S(25) S(26) S(27) S(28) S(29)
    S(30) S(31) S(32) S(33) S(34) S(35) S(36) S(37) S(38) S(39)
    S(40) S(41) S(42) S(43) S(44) S(45) S(46) S(47) S(48) S(49)

    float d = x2 - g;
    out[b]         = d * d;   // loss
    out[B + b]     = x1;
    out[2 * B + b] = x2;
}

extern "C" void kernel_launch(void* const* d_in, const int* in_sizes, int n_in,
                              void* d_out, int out_size, void* d_ws, size_t ws_size,
                              hipStream_t stream) {
    const float* u_seq = (const float*)d_in[0];
    const float* x1_0  = (const float*)d_in[1];
    const float* v1_0  = (const float*)d_in[2];
    const float* x2_0  = (const float*)d_in[3];
    const float* v2_0  = (const float*)d_in[4];
    const float* goal  = (const float*)d_in[5];
    float* out = (float*)d_out;

    const int B = in_sizes[1];  // 131072
    const int block = 256;
    const int grid = B / block; // 512 blocks
    pushing_env_kernel<<<grid, block, 0, stream>>>(u_seq, x1_0, v1_0, x2_0,
                                                   v2_0, goal, out, B);
}